// Round 2
// baseline (293.753 us; speedup 1.0000x reference)
//
#include <hip/hip_runtime.h>
#include <hip/hip_bf16.h>

#define HDIM 128

typedef __attribute__((ext_vector_type(8))) short short8;
typedef __attribute__((ext_vector_type(4))) float floatx4;

__device__ __forceinline__ float bf2f(unsigned short u) {
    return __uint_as_float(((unsigned)u) << 16);
}
__device__ __forceinline__ unsigned short f2b(float f) {
    __hip_bfloat16 h = __float2bfloat16(f);
    return __builtin_bit_cast(unsigned short, h);
}
__device__ __forceinline__ float ldv(const void* p, size_t i, int flag) {
    return flag ? bf2f(((const unsigned short*)p)[i]) : ((const float*)p)[i];
}

// ---------------------------------------------------------------------------
// detect: flag=1 if z_gene bits look like bf16, flag=0 if float32.
// bf16 N(0,1) data: ~100% of u16s have exponent in plausible band.
// f32 data reinterpreted as u16 pairs: high halves plausible (~100%), low
// halves ~uniform (~16% in band) -> total ~58%. Threshold at 90%.
// ---------------------------------------------------------------------------
__global__ __launch_bounds__(256) void detect_kernel(
    const unsigned short* __restrict__ zbits, int* __restrict__ flag)
{
    __shared__ int red[256];
    int tid = threadIdx.x;
    int cnt = 0;
    for (int i = tid; i < 4096; i += 256) {
        int ex = (zbits[i] >> 7) & 0xFF;
        if (ex >= 100 && ex <= 140) cnt++;
    }
    red[tid] = cnt;
    __syncthreads();
    for (int s = 128; s > 0; s >>= 1) {
        if (tid < s) red[tid] += red[tid + s];
        __syncthreads();
    }
    if (tid == 0) *flag = (red[0] >= 3686) ? 1 : 0;
}

// ---------------------------------------------------------------------------
// convert: src (f32 or bf16 per flag) -> canonical bf16, 4 elements/thread.
// ---------------------------------------------------------------------------
__global__ __launch_bounds__(256) void convert_kernel(
    const void* __restrict__ src, unsigned short* __restrict__ dst,
    int n4, const int* __restrict__ flagp)
{
    int i = blockIdx.x * 256 + threadIdx.x;
    if (i >= n4) return;
    ushort4 v;
    if (*flagp) {
        v = ((const ushort4*)src)[i];
    } else {
        float4 f = ((const float4*)src)[i];
        v.x = f2b(f.x); v.y = f2b(f.y); v.z = f2b(f.z); v.w = f2b(f.w);
    }
    ((ushort4*)dst)[i] = v;
}

// ---------------------------------------------------------------------------
// wprep: blocks 0-3 build swizzled, transposed 128x128 bf16 W images.
// img[b][n*128 + (g^(n&15))*8 + j] = w1[(part*128+g*8+j)*128 + n]
// block 4 converts small params to f32:
//   params[0:128)=b1_gd [128:256)=w2_gd [256:384)=b1_gg [384:512)=w2_gg
//   params[512]=b2_gd params[513]=b2_gg
// ---------------------------------------------------------------------------
__global__ __launch_bounds__(256) void wprep_kernel(
    const void* __restrict__ w1_gd, const void* __restrict__ w1_gg,
    const void* __restrict__ b1_gd, const void* __restrict__ w2_gd,
    const void* __restrict__ b2_gd, const void* __restrict__ b1_gg,
    const void* __restrict__ w2_gg, const void* __restrict__ b2_gg,
    unsigned short* __restrict__ img, float* __restrict__ params,
    const int* __restrict__ flagp)
{
    int b = blockIdx.x;
    int flag = *flagp;
    if (b < 4) {
        const void* w1 = (b < 2) ? w1_gd : w1_gg;
        int part = b & 1;
        unsigned short* out = img + b * 16384;
        for (int idx = threadIdx.x; idx < 16384; idx += 256) {
            int n   = idx >> 7;
            int rem = idx & 127;
            int g   = (rem >> 3) ^ (n & 15);
            int j   = rem & 7;
            size_t s = (size_t)(part * 128 + g * 8 + j) * 128 + n;
            out[idx] = flag ? ((const unsigned short*)w1)[s]
                            : f2b(((const float*)w1)[s]);
        }
    } else {
        int t = threadIdx.x;
        if (t < 128) {
            params[t]       = ldv(b1_gd, t, flag);
            params[256 + t] = ldv(b1_gg, t, flag);
        } else {
            params[t]       = ldv(w2_gd, t - 128, flag);
            params[256 + t] = ldv(w2_gg, t - 128, flag);
        }
        if (t == 0) {
            params[512] = ldv(b2_gd, 0, flag);
            params[513] = ldv(b2_gg, 0, flag);
        }
    }
}

// ---------------------------------------------------------------------------
// proj: Out[M x 128] = Z[M x 128] @ W[128 x 128]  (canonical bf16 in/out).
// Pre-swizzled W image staged to LDS; W is the MFMA A-operand (m = out col),
// Z is the B-operand (n = out row) so each lane's 4 accum regs are 4
// consecutive columns of one row -> ushort4 store.
// ---------------------------------------------------------------------------
__global__ __launch_bounds__(256) void proj_kernel(
    const unsigned short* __restrict__ Z,
    const uint4* __restrict__ Wimg,
    unsigned short* __restrict__ Out,
    int M)
{
    __shared__ uint4 sW[2048];  // 32 KB
    int tid = threadIdx.x;
#pragma unroll
    for (int i = 0; i < 8; ++i) sW[tid + i * 256] = Wimg[tid + i * 256];
    __syncthreads();

    int lane = tid & 63;
    int wave = tid >> 6;
    int nl   = lane & 15;   // Z-row in tile / W-col in tile
    int quad = lane >> 4;   // k-chunk quad

    int row0 = blockIdx.x * 128 + wave * 32 + nl;
    int row1 = row0 + 16;
    int r0c = row0 < M ? row0 : (M - 1);
    int r1c = row1 < M ? row1 : (M - 1);
    const uint4* z0 = (const uint4*)Z + (size_t)r0c * 16;
    const uint4* z1 = (const uint4*)Z + (size_t)r1c * 16;

    floatx4 acc[2][8];
#pragma unroll
    for (int rt = 0; rt < 2; ++rt)
#pragma unroll
        for (int nt = 0; nt < 8; ++nt)
            acc[rt][nt] = (floatx4){0.f, 0.f, 0.f, 0.f};

#pragma unroll
    for (int kc = 0; kc < 4; ++kc) {
        short8 zf0 = __builtin_bit_cast(short8, z0[kc * 4 + quad]);
        short8 zf1 = __builtin_bit_cast(short8, z1[kc * 4 + quad]);
#pragma unroll
        for (int nt = 0; nt < 8; ++nt) {
            int ng = nt * 16 + nl;
            int p  = (kc * 4 + quad) ^ nl;   // undo XOR swizzle
            short8 wf = __builtin_bit_cast(short8, sW[ng * 16 + p]);
            acc[0][nt] = __builtin_amdgcn_mfma_f32_16x16x32_bf16(wf, zf0, acc[0][nt], 0, 0, 0);
            acc[1][nt] = __builtin_amdgcn_mfma_f32_16x16x32_bf16(wf, zf1, acc[1][nt], 0, 0, 0);
        }
    }

    // D: lane holds D[m=quad*4+i][n=nl]; m = out col, n = out row.
#pragma unroll
    for (int rt = 0; rt < 2; ++rt) {
        int row = rt ? row1 : row0;
        if (row < M) {
#pragma unroll
            for (int nt = 0; nt < 8; ++nt) {
                ushort4 v;
                v.x = f2b(acc[rt][nt][0]);
                v.y = f2b(acc[rt][nt][1]);
                v.z = f2b(acc[rt][nt][2]);
                v.w = f2b(acc[rt][nt][3]);
                *(ushort4*)(Out + (size_t)row * HDIM + nt * 16 + quad * 4) = v;
            }
        }
    }
}

// ---------------------------------------------------------------------------
// edge: out[eoff+e] = relu(A[src]+B[dst]+b1) . w2 + b2
// 16 lanes/edge, 8 channels/lane, shfl_xor reduce; store f32 or bf16 per flag.
// pp: [0:128)=b1 f32, [128:256)=w2 f32; pb2: &b2 f32.
// ---------------------------------------------------------------------------
__global__ __launch_bounds__(256) void edge_kernel(
    const int* __restrict__ edges,
    const unsigned short* __restrict__ A,
    const unsigned short* __restrict__ B,
    const float* __restrict__ pp,
    const float* __restrict__ pb2,
    void* __restrict__ out, size_t eoff, int E,
    const int* __restrict__ flagp)
{
    int tid  = threadIdx.x;
    int lane = tid & 63;
    int wave = tid >> 6;
    int nl   = lane & 15;
    int grp  = lane >> 4;

    float4 b1a = *(const float4*)(pp + nl * 8);
    float4 b1b = *(const float4*)(pp + nl * 8 + 4);
    float4 w2a = *(const float4*)(pp + 128 + nl * 8);
    float4 w2b = *(const float4*)(pp + 128 + nl * 8 + 4);
    float b1f[8] = {b1a.x, b1a.y, b1a.z, b1a.w, b1b.x, b1b.y, b1b.z, b1b.w};
    float w2f[8] = {w2a.x, w2a.y, w2a.z, w2a.w, w2b.x, w2b.y, w2b.z, w2b.w};
    float b2f = *pb2;

    int e = blockIdx.x * 16 + wave * 4 + grp;
    float acc = 0.f;
    if (e < E) {
        int src = edges[e];
        int dst = edges[E + e];
        uint4 av = *((const uint4*)(A + (size_t)src * HDIM) + nl);
        uint4 bv = *((const uint4*)(B + (size_t)dst * HDIM) + nl);
        const unsigned* au = (const unsigned*)&av;
        const unsigned* bu = (const unsigned*)&bv;
#pragma unroll
        for (int i = 0; i < 4; ++i) {
            float a0 = __uint_as_float(au[i] << 16);
            float a1 = __uint_as_float(au[i] & 0xffff0000u);
            float c0 = __uint_as_float(bu[i] << 16);
            float c1 = __uint_as_float(bu[i] & 0xffff0000u);
            float h0 = fmaxf(a0 + c0 + b1f[2 * i], 0.f);
            float h1 = fmaxf(a1 + c1 + b1f[2 * i + 1], 0.f);
            acc = fmaf(h0, w2f[2 * i], acc);
            acc = fmaf(h1, w2f[2 * i + 1], acc);
        }
    }
    acc += __shfl_xor(acc, 1);
    acc += __shfl_xor(acc, 2);
    acc += __shfl_xor(acc, 4);
    acc += __shfl_xor(acc, 8);
    if (e < E && nl == 0) {
        float r = acc + b2f;
        if (*flagp) ((unsigned short*)out)[eoff + e] = f2b(r);
        else        ((float*)out)[eoff + e] = r;
    }
}

// ---------------------------------------------------------------------------
// Fallback: full per-edge MLP, one edge / block, dual-dtype via flag.
// flagp==nullptr -> assume f32 (reference dtype).
// ---------------------------------------------------------------------------
__global__ __launch_bounds__(128) void naive_edge_kernel(
    const int* __restrict__ edges,
    const void* __restrict__ zsrc, const void* __restrict__ zdst,
    const void* __restrict__ w1, const void* __restrict__ b1,
    const void* __restrict__ w2, const void* __restrict__ b2,
    void* __restrict__ out, size_t eoff, int E,
    const int* __restrict__ flagp)
{
    int flag = flagp ? *flagp : 0;
    __shared__ float zs[128], zd[128], red[128];
    int e = blockIdx.x;
    int n = threadIdx.x;
    int src = edges[e], dst = edges[E + e];
    zs[n] = ldv(zsrc, (size_t)src * HDIM + n, flag);
    zd[n] = ldv(zdst, (size_t)dst * HDIM + n, flag);
    __syncthreads();
    float acc = ldv(b1, n, flag);
    for (int k = 0; k < 128; ++k) acc = fmaf(zs[k], ldv(w1, (size_t)k * HDIM + n, flag), acc);
    for (int k = 0; k < 128; ++k) acc = fmaf(zd[k], ldv(w1, (size_t)(128 + k) * HDIM + n, flag), acc);
    red[n] = fmaxf(acc, 0.f) * ldv(w2, n, flag);
    __syncthreads();
    for (int s = 64; s > 0; s >>= 1) {
        if (n < s) red[n] += red[n + s];
        __syncthreads();
    }
    if (n == 0) {
        float r = red[0] + ldv(b2, 0, flag);
        if (flag) ((unsigned short*)out)[eoff + e] = f2b(r);
        else      ((float*)out)[eoff + e] = r;
    }
}

extern "C" void kernel_launch(void* const* d_in, const int* in_sizes, int n_in,
                              void* d_out, int out_size, void* d_ws, size_t ws_size,
                              hipStream_t stream)
{
    const void* z_gene = d_in[0];
    const void* z_dis  = d_in[1];
    const int* edges_gd = (const int*)d_in[2];
    const int* edges_gg = (const int*)d_in[3];
    const void* w1_gd = d_in[4];
    const void* b1_gd = d_in[5];
    const void* w2_gd = d_in[6];
    const void* b2_gd = d_in[7];
    const void* w1_gg = d_in[8];
    const void* b1_gg = d_in[9];
    const void* w2_gg = d_in[10];
    const void* b2_gg = d_in[11];

    int NG = in_sizes[0] / HDIM;   // 100000
    int ND = in_sizes[1] / HDIM;   // 20000
    int E  = in_sizes[2] / 2;      // 500000

    // workspace layout (bytes, 256-aligned)
    size_t off_flag   = 0;
    size_t off_params = 256;
    size_t off_img    = 256 + 2304;                       // 516 f32 padded
    size_t off_Zg     = off_img + 131072;
    size_t off_Zd     = off_Zg + (size_t)NG * HDIM * 2;
    size_t off_Agd    = off_Zd + (size_t)ND * HDIM * 2;
    size_t off_Bgd    = off_Agd + (size_t)NG * HDIM * 2;
    size_t off_Agg    = off_Bgd + (size_t)ND * HDIM * 2;
    size_t off_Bgg    = off_Agg + (size_t)NG * HDIM * 2;
    size_t need       = off_Bgg + (size_t)NG * HDIM * 2;

    char* ws = (char*)d_ws;

    if (ws_size < need) {
        const int* flagp = nullptr;
        if (ws_size >= 16) {
            detect_kernel<<<1, 256, 0, stream>>>((const unsigned short*)z_gene, (int*)ws);
            flagp = (const int*)ws;
        }
        naive_edge_kernel<<<E, 128, 0, stream>>>(edges_gd, z_gene, z_dis,
                                                 w1_gd, b1_gd, w2_gd, b2_gd,
                                                 d_out, 0, E, flagp);
        naive_edge_kernel<<<E, 128, 0, stream>>>(edges_gg, z_gene, z_gene,
                                                 w1_gg, b1_gg, w2_gg, b2_gg,
                                                 d_out, (size_t)E, E, flagp);
        return;
    }

    int* flag = (int*)(ws + off_flag);
    float* params = (float*)(ws + off_params);
    unsigned short* img = (unsigned short*)(ws + off_img);
    unsigned short* Zg  = (unsigned short*)(ws + off_Zg);
    unsigned short* Zd  = (unsigned short*)(ws + off_Zd);
    unsigned short* Agd = (unsigned short*)(ws + off_Agd);
    unsigned short* Bgd = (unsigned short*)(ws + off_Bgd);
    unsigned short* Agg = (unsigned short*)(ws + off_Agg);
    unsigned short* Bgg = (unsigned short*)(ws + off_Bgg);

    detect_kernel<<<1, 256, 0, stream>>>((const unsigned short*)z_gene, flag);

    int ng4 = NG * HDIM / 4, nd4 = ND * HDIM / 4;
    convert_kernel<<<(ng4 + 255) / 256, 256, 0, stream>>>(z_gene, Zg, ng4, flag);
    convert_kernel<<<(nd4 + 255) / 256, 256, 0, stream>>>(z_dis,  Zd, nd4, flag);

    wprep_kernel<<<5, 256, 0, stream>>>(w1_gd, w1_gg, b1_gd, w2_gd, b2_gd,
                                        b1_gg, w2_gg, b2_gg, img, params, flag);

    const uint4* img4 = (const uint4*)img;
    int gblk = (NG + 127) / 128;
    int dblk = (ND + 127) / 128;
    proj_kernel<<<gblk, 256, 0, stream>>>(Zg, img4,        Agd, NG);
    proj_kernel<<<dblk, 256, 0, stream>>>(Zd, img4 + 2048, Bgd, ND);
    proj_kernel<<<gblk, 256, 0, stream>>>(Zg, img4 + 4096, Agg, NG);
    proj_kernel<<<gblk, 256, 0, stream>>>(Zg, img4 + 6144, Bgg, NG);

    int eblk = (E + 15) / 16;
    edge_kernel<<<eblk, 256, 0, stream>>>(edges_gd, Agd, Bgd, params,
                                          params + 512, d_out, 0, E, flag);
    edge_kernel<<<eblk, 256, 0, stream>>>(edges_gg, Agg, Bgg, params + 256,
                                          params + 513, d_out, (size_t)E, E, flag);
}

// Round 3
// 251.872 us; speedup vs baseline: 1.1663x; 1.1663x over previous
//
#include <hip/hip_runtime.h>
#include <hip/hip_bf16.h>

#define HDIM 128

typedef __attribute__((ext_vector_type(8))) short short8;
typedef __attribute__((ext_vector_type(4))) float floatx4;

__device__ __forceinline__ float bf2f(unsigned short u) {
    return __uint_as_float(((unsigned)u) << 16);
}
__device__ __forceinline__ unsigned short f2b(float f) {
    __hip_bfloat16 h = __float2bfloat16(f);
    return __builtin_bit_cast(unsigned short, h);
}
__device__ __forceinline__ float ldv(const void* p, size_t i, int flag) {
    return flag ? bf2f(((const unsigned short*)p)[i]) : ((const float*)p)[i];
}
__device__ __forceinline__ short8 pack8(float4 a, float4 b) {
    short8 r;
    r[0] = (short)f2b(a.x); r[1] = (short)f2b(a.y);
    r[2] = (short)f2b(a.z); r[3] = (short)f2b(a.w);
    r[4] = (short)f2b(b.x); r[5] = (short)f2b(b.y);
    r[6] = (short)f2b(b.z); r[7] = (short)f2b(b.w);
    return r;
}

// ---------------------------------------------------------------------------
// detect: flag=1 if z_gene bits look like bf16, 0 if float32 (low halves of
// f32 are ~uniform u16s -> only ~58% have plausible exponents vs ~100%).
// ---------------------------------------------------------------------------
__global__ __launch_bounds__(256) void detect_kernel(
    const unsigned short* __restrict__ zbits, int* __restrict__ flag)
{
    __shared__ int red[256];
    int tid = threadIdx.x;
    int cnt = 0;
    for (int i = tid; i < 4096; i += 256) {
        int ex = (zbits[i] >> 7) & 0xFF;
        if (ex >= 100 && ex <= 140) cnt++;
    }
    red[tid] = cnt;
    __syncthreads();
    for (int s = 128; s > 0; s >>= 1) {
        if (tid < s) red[tid] += red[tid + s];
        __syncthreads();
    }
    if (tid == 0) *flag = (red[0] >= 3686) ? 1 : 0;
}

// ---------------------------------------------------------------------------
// wprep: blocks 0-3 build swizzled, transposed 128x128 bf16 W images.
// img[b][n*128 + (g^(n&15))*8 + j] = w1[(part*128+g*8+j)*128 + n]
// b: 0=gd_top 1=gd_bot 2=gg_top 3=gg_bot.  Block 4: params to f32:
// [0:128)=b1_gd [128:256)=w2_gd [256:384)=b1_gg [384:512)=w2_gg
// [512]=b2_gd [513]=b2_gg
// ---------------------------------------------------------------------------
__global__ __launch_bounds__(256) void wprep_kernel(
    const void* __restrict__ w1_gd, const void* __restrict__ w1_gg,
    const void* __restrict__ b1_gd, const void* __restrict__ w2_gd,
    const void* __restrict__ b2_gd, const void* __restrict__ b1_gg,
    const void* __restrict__ w2_gg, const void* __restrict__ b2_gg,
    unsigned short* __restrict__ img, float* __restrict__ params,
    const int* __restrict__ flagp)
{
    int b = blockIdx.x;
    int flag = *flagp;
    if (b < 4) {
        const void* w1 = (b < 2) ? w1_gd : w1_gg;
        int part = b & 1;
        unsigned short* out = img + b * 16384;
        for (int idx = threadIdx.x; idx < 16384; idx += 256) {
            int n   = idx >> 7;
            int rem = idx & 127;
            int g   = (rem >> 3) ^ (n & 15);
            int j   = rem & 7;
            size_t s = (size_t)(part * 128 + g * 8 + j) * 128 + n;
            out[idx] = flag ? ((const unsigned short*)w1)[s]
                            : f2b(((const float*)w1)[s]);
        }
    } else {
        int t = threadIdx.x;
        if (t < 128) {
            params[t]       = ldv(b1_gd, t, flag);
            params[256 + t] = ldv(b1_gg, t, flag);
        } else {
            params[t]       = ldv(w2_gd, t - 128, flag);
            params[256 + t] = ldv(w2_gg, t - 128, flag);
        }
        if (t == 0) {
            params[512] = ldv(b2_gd, 0, flag);
            params[513] = ldv(b2_gg, 0, flag);
        }
    }
}

// ---------------------------------------------------------------------------
// Z fragment load: 2 rows x 4 kc fragments (short8 each) per lane, direct
// from global in either dtype. Row layout: 128 elems; lane (nl,quad) needs
// cols [kc*32+quad*8, +8).
// ---------------------------------------------------------------------------
__device__ __forceinline__ void load_zfrags(
    const void* Z, int r0c, int r1c, int quad, int flag, short8 zf[2][4])
{
    if (flag) {
        const uint4* z0 = (const uint4*)Z + (size_t)r0c * 16;
        const uint4* z1 = (const uint4*)Z + (size_t)r1c * 16;
#pragma unroll
        for (int kc = 0; kc < 4; ++kc) {
            zf[0][kc] = __builtin_bit_cast(short8, z0[kc * 4 + quad]);
            zf[1][kc] = __builtin_bit_cast(short8, z1[kc * 4 + quad]);
        }
    } else {
        const float4* z0 = (const float4*)Z + (size_t)r0c * 32;
        const float4* z1 = (const float4*)Z + (size_t)r1c * 32;
#pragma unroll
        for (int kc = 0; kc < 4; ++kc) {
            int o = kc * 8 + quad * 2;
            zf[0][kc] = pack8(z0[o], z0[o + 1]);
            zf[1][kc] = pack8(z1[o], z1[o + 1]);
        }
    }
}

// ---------------------------------------------------------------------------
// One 128x128 MFMA pass against the W image currently in LDS.
// W = A-operand (m = out col), Z = B-operand (n = out row); lane's 4 accum
// regs = 4 consecutive out cols of one row -> ushort4 stores.
// ---------------------------------------------------------------------------
__device__ __forceinline__ void mfma_pass_store(
    const uint4* sW, const short8 zf[2][4], int nl, int quad,
    int row0, int row1, int M, unsigned short* __restrict__ Out)
{
    floatx4 acc[2][8];
#pragma unroll
    for (int rt = 0; rt < 2; ++rt)
#pragma unroll
        for (int nt = 0; nt < 8; ++nt)
            acc[rt][nt] = (floatx4){0.f, 0.f, 0.f, 0.f};

#pragma unroll
    for (int kc = 0; kc < 4; ++kc) {
        int p = (kc * 4 + quad) ^ nl;   // undo XOR swizzle
#pragma unroll
        for (int nt = 0; nt < 8; ++nt) {
            short8 wf = __builtin_bit_cast(short8, sW[(nt * 16 + nl) * 16 + p]);
            acc[0][nt] = __builtin_amdgcn_mfma_f32_16x16x32_bf16(wf, zf[0][kc], acc[0][nt], 0, 0, 0);
            acc[1][nt] = __builtin_amdgcn_mfma_f32_16x16x32_bf16(wf, zf[1][kc], acc[1][nt], 0, 0, 0);
        }
    }
#pragma unroll
    for (int rt = 0; rt < 2; ++rt) {
        int row = rt ? row1 : row0;
        if (row < M) {
#pragma unroll
            for (int nt = 0; nt < 8; ++nt) {
                ushort4 v;
                v.x = f2b(acc[rt][nt][0]);
                v.y = f2b(acc[rt][nt][1]);
                v.z = f2b(acc[rt][nt][2]);
                v.w = f2b(acc[rt][nt][3]);
                *(ushort4*)(Out + (size_t)row * HDIM + nt * 16 + quad * 4) = v;
            }
        }
    }
}

// ---------------------------------------------------------------------------
// proj_gene3: read z_gene ONCE (fragments in registers), then 3 phases each
// staging one 32KB W image into the same LDS buffer:
//   ph0: img0 (gd_top) -> A_gd   ph1: img2 (gg_top) -> A_gg
//   ph2: img3 (gg_bot) -> B_gg
// ---------------------------------------------------------------------------
__global__ __launch_bounds__(256) void proj_gene3_kernel(
    const void* __restrict__ Z, const uint4* __restrict__ Wimg,
    unsigned short* __restrict__ A_gd, unsigned short* __restrict__ A_gg,
    unsigned short* __restrict__ B_gg, int M, const int* __restrict__ flagp)
{
    __shared__ uint4 sW[2048];  // 32 KB
    int tid  = threadIdx.x;
    int lane = tid & 63;
    int wave = tid >> 6;
    int nl   = lane & 15;
    int quad = lane >> 4;

    int row0 = blockIdx.x * 128 + wave * 32 + nl;
    int row1 = row0 + 16;
    int r0c = row0 < M ? row0 : (M - 1);
    int r1c = row1 < M ? row1 : (M - 1);

    short8 zf[2][4];
    load_zfrags(Z, r0c, r1c, quad, *flagp, zf);

    const uint4* imgs[3] = {Wimg, Wimg + 2 * 2048, Wimg + 3 * 2048};
    unsigned short* outs[3] = {A_gd, A_gg, B_gg};
#pragma unroll
    for (int ph = 0; ph < 3; ++ph) {
        __syncthreads();   // previous phase readers done before overwrite
        const uint4* im = imgs[ph];
#pragma unroll
        for (int i = 0; i < 8; ++i) sW[tid + i * 256] = im[tid + i * 256];
        __syncthreads();
        mfma_pass_store(sW, zf, nl, quad, row0, row1, M, outs[ph]);
    }
}

// ---------------------------------------------------------------------------
// proj1: single-image projection (z_disease @ gd_bot -> B_gd).
// ---------------------------------------------------------------------------
__global__ __launch_bounds__(256) void proj1_kernel(
    const void* __restrict__ Z, const uint4* __restrict__ Wimg,
    unsigned short* __restrict__ Out, int M, const int* __restrict__ flagp)
{
    __shared__ uint4 sW[2048];
    int tid  = threadIdx.x;
    int lane = tid & 63;
    int wave = tid >> 6;
    int nl   = lane & 15;
    int quad = lane >> 4;

    int row0 = blockIdx.x * 128 + wave * 32 + nl;
    int row1 = row0 + 16;
    int r0c = row0 < M ? row0 : (M - 1);
    int r1c = row1 < M ? row1 : (M - 1);

    short8 zf[2][4];
    load_zfrags(Z, r0c, r1c, quad, *flagp, zf);

#pragma unroll
    for (int i = 0; i < 8; ++i) sW[tid + i * 256] = Wimg[tid + i * 256];
    __syncthreads();
    mfma_pass_store(sW, zf, nl, quad, row0, row1, M, Out);
}

// ---------------------------------------------------------------------------
// edge (both relations, one grid): out[eoff+e] = relu(A[src]+B[dst]+b1).w2+b2
// 8 lanes/edge, 16 channels (32 B) per lane -> 4 outstanding uint4 loads.
// ---------------------------------------------------------------------------
__global__ __launch_bounds__(256) void edge_kernel(
    const int* __restrict__ edges_gd, const int* __restrict__ edges_gg,
    const unsigned short* __restrict__ A_gd, const unsigned short* __restrict__ B_gd,
    const unsigned short* __restrict__ A_gg, const unsigned short* __restrict__ B_gg,
    const float* __restrict__ params,
    void* __restrict__ out, int E, int eblk, const int* __restrict__ flagp)
{
    int rel = (blockIdx.x >= eblk) ? 1 : 0;
    int blk = blockIdx.x - rel * eblk;
    const int* edges = rel ? edges_gg : edges_gd;
    const unsigned short* A = rel ? A_gg : A_gd;
    const unsigned short* B = rel ? B_gg : B_gd;
    const float* pp = params + rel * 256;
    float b2f = params[512 + rel];
    size_t eoff = rel ? (size_t)E : 0;

    int tid  = threadIdx.x;
    int lane = tid & 63;
    int wave = tid >> 6;
    int nl   = lane & 7;    // 8 lanes per edge
    int grp  = lane >> 3;   // 8 edges per wave

    float b1f[16], w2f[16];
#pragma unroll
    for (int i = 0; i < 4; ++i) {
        float4 tb = *(const float4*)(pp + nl * 16 + i * 4);
        float4 tw = *(const float4*)(pp + 128 + nl * 16 + i * 4);
        b1f[i * 4 + 0] = tb.x; b1f[i * 4 + 1] = tb.y;
        b1f[i * 4 + 2] = tb.z; b1f[i * 4 + 3] = tb.w;
        w2f[i * 4 + 0] = tw.x; w2f[i * 4 + 1] = tw.y;
        w2f[i * 4 + 2] = tw.z; w2f[i * 4 + 3] = tw.w;
    }

    int e = blk * 32 + wave * 8 + grp;
    float acc = 0.f;
    if (e < E) {
        int src = edges[e];
        int dst = edges[E + e];
        const uint4* ap = (const uint4*)(A + (size_t)src * HDIM) + nl * 2;
        const uint4* bp = (const uint4*)(B + (size_t)dst * HDIM) + nl * 2;
        uint4 a0 = ap[0], a1 = ap[1];
        uint4 c0 = bp[0], c1 = bp[1];
        const unsigned* au0 = (const unsigned*)&a0;
        const unsigned* au1 = (const unsigned*)&a1;
        const unsigned* cu0 = (const unsigned*)&c0;
        const unsigned* cu1 = (const unsigned*)&c1;
#pragma unroll
        for (int i = 0; i < 4; ++i) {
            float x0 = __uint_as_float(au0[i] << 16);
            float x1 = __uint_as_float(au0[i] & 0xffff0000u);
            float y0 = __uint_as_float(cu0[i] << 16);
            float y1 = __uint_as_float(cu0[i] & 0xffff0000u);
            float h0 = fmaxf(x0 + y0 + b1f[2 * i], 0.f);
            float h1 = fmaxf(x1 + y1 + b1f[2 * i + 1], 0.f);
            acc = fmaf(h0, w2f[2 * i], acc);
            acc = fmaf(h1, w2f[2 * i + 1], acc);
        }
#pragma unroll
        for (int i = 0; i < 4; ++i) {
            float x0 = __uint_as_float(au1[i] << 16);
            float x1 = __uint_as_float(au1[i] & 0xffff0000u);
            float y0 = __uint_as_float(cu1[i] << 16);
            float y1 = __uint_as_float(cu1[i] & 0xffff0000u);
            float h0 = fmaxf(x0 + y0 + b1f[8 + 2 * i], 0.f);
            float h1 = fmaxf(x1 + y1 + b1f[8 + 2 * i + 1], 0.f);
            acc = fmaf(h0, w2f[8 + 2 * i], acc);
            acc = fmaf(h1, w2f[8 + 2 * i + 1], acc);
        }
    }
    acc += __shfl_xor(acc, 1);
    acc += __shfl_xor(acc, 2);
    acc += __shfl_xor(acc, 4);
    if (e < E && nl == 0) {
        float r = acc + b2f;
        if (*flagp) ((unsigned short*)out)[eoff + e] = f2b(r);
        else        ((float*)out)[eoff + e] = r;
    }
}

// ---------------------------------------------------------------------------
// Fallback: full per-edge MLP, one edge / block (only if ws too small).
// ---------------------------------------------------------------------------
__global__ __launch_bounds__(128) void naive_edge_kernel(
    const int* __restrict__ edges,
    const void* __restrict__ zsrc, const void* __restrict__ zdst,
    const void* __restrict__ w1, const void* __restrict__ b1,
    const void* __restrict__ w2, const void* __restrict__ b2,
    void* __restrict__ out, size_t eoff, int E,
    const int* __restrict__ flagp)
{
    int flag = flagp ? *flagp : 0;
    __shared__ float zs[128], zd[128], red[128];
    int e = blockIdx.x;
    int n = threadIdx.x;
    int src = edges[e], dst = edges[E + e];
    zs[n] = ldv(zsrc, (size_t)src * HDIM + n, flag);
    zd[n] = ldv(zdst, (size_t)dst * HDIM + n, flag);
    __syncthreads();
    float acc = ldv(b1, n, flag);
    for (int k = 0; k < 128; ++k) acc = fmaf(zs[k], ldv(w1, (size_t)k * HDIM + n, flag), acc);
    for (int k = 0; k < 128; ++k) acc = fmaf(zd[k], ldv(w1, (size_t)(128 + k) * HDIM + n, flag), acc);
    red[n] = fmaxf(acc, 0.f) * ldv(w2, n, flag);
    __syncthreads();
    for (int s = 64; s > 0; s >>= 1) {
        if (n < s) red[n] += red[n + s];
        __syncthreads();
    }
    if (n == 0) {
        float r = red[0] + ldv(b2, 0, flag);
        if (flag) ((unsigned short*)out)[eoff + e] = f2b(r);
        else      ((float*)out)[eoff + e] = r;
    }
}

extern "C" void kernel_launch(void* const* d_in, const int* in_sizes, int n_in,
                              void* d_out, int out_size, void* d_ws, size_t ws_size,
                              hipStream_t stream)
{
    const void* z_gene = d_in[0];
    const void* z_dis  = d_in[1];
    const int* edges_gd = (const int*)d_in[2];
    const int* edges_gg = (const int*)d_in[3];
    const void* w1_gd = d_in[4];
    const void* b1_gd = d_in[5];
    const void* w2_gd = d_in[6];
    const void* b2_gd = d_in[7];
    const void* w1_gg = d_in[8];
    const void* b1_gg = d_in[9];
    const void* w2_gg = d_in[10];
    const void* b2_gg = d_in[11];

    int NG = in_sizes[0] / HDIM;   // 100000
    int ND = in_sizes[1] / HDIM;   // 20000
    int E  = in_sizes[2] / 2;      // 500000

    // workspace layout (bytes)
    size_t off_flag   = 0;
    size_t off_params = 256;
    size_t off_img    = 2560;
    size_t off_Agd    = off_img + 131072;
    size_t off_Bgd    = off_Agd + (size_t)NG * HDIM * 2;
    size_t off_Agg    = off_Bgd + (size_t)ND * HDIM * 2;
    size_t off_Bgg    = off_Agg + (size_t)NG * HDIM * 2;
    size_t need       = off_Bgg + (size_t)NG * HDIM * 2;

    char* ws = (char*)d_ws;

    if (ws_size < need) {
        const int* flagp = nullptr;
        if (ws_size >= 16) {
            detect_kernel<<<1, 256, 0, stream>>>((const unsigned short*)z_gene, (int*)ws);
            flagp = (const int*)ws;
        }
        naive_edge_kernel<<<E, 128, 0, stream>>>(edges_gd, z_gene, z_dis,
                                                 w1_gd, b1_gd, w2_gd, b2_gd,
                                                 d_out, 0, E, flagp);
        naive_edge_kernel<<<E, 128, 0, stream>>>(edges_gg, z_gene, z_gene,
                                                 w1_gg, b1_gg, w2_gg, b2_gg,
                                                 d_out, (size_t)E, E, flagp);
        return;
    }

    int* flag = (int*)(ws + off_flag);
    float* params = (float*)(ws + off_params);
    unsigned short* img = (unsigned short*)(ws + off_img);
    unsigned short* Agd = (unsigned short*)(ws + off_Agd);
    unsigned short* Bgd = (unsigned short*)(ws + off_Bgd);
    unsigned short* Agg = (unsigned short*)(ws + off_Agg);
    unsigned short* Bgg = (unsigned short*)(ws + off_Bgg);

    detect_kernel<<<1, 256, 0, stream>>>((const unsigned short*)z_gene, flag);

    wprep_kernel<<<5, 256, 0, stream>>>(w1_gd, w1_gg, b1_gd, w2_gd, b2_gd,
                                        b1_gg, w2_gg, b2_gg, img, params, flag);

    const uint4* img4 = (const uint4*)img;
    int gblk = (NG + 127) / 128;
    int dblk = (ND + 127) / 128;
    proj_gene3_kernel<<<gblk, 256, 0, stream>>>(z_gene, img4, Agd, Agg, Bgg, NG, flag);
    proj1_kernel<<<dblk, 256, 0, stream>>>(z_dis, img4 + 2048, Bgd, ND, flag);

    int eblk = (E + 31) / 32;
    edge_kernel<<<2 * eblk, 256, 0, stream>>>(edges_gd, edges_gg, Agd, Bgd, Agg, Bgg,
                                              params, d_out, E, eblk, flag);
}